// Round 24
// baseline (40.506 us; speedup 1.0000x reference)
//
#include <hip/hip_runtime.h>
#include <math.h>

#define N_EXP 64
#define TOPK 8
#define TOPK_G 4
#define D_DIM 2048
#define S_TOT 16384
#define RPB 64            // rows per block
#define NBUF 5            // LDS pipeline depth (160 KB = full CU)
#define NCH 32            // K chunks of 64

typedef _Float16 half8 __attribute__((ext_vector_type(8)));
typedef float f32x4 __attribute__((ext_vector_type(4)));

typedef __attribute__((address_space(1))) const unsigned int ga_u32;
typedef __attribute__((address_space(3))) unsigned int ls_u32;
#define GLL(src, dst) \
    __builtin_amdgcn_global_load_lds((ga_u32*)(src), (ls_u32*)(dst), 16, 0, 0)
#define VM(n) asm volatile("s_waitcnt vmcnt(" #n ")" ::: "memory")
#define BAR() do { asm volatile("" ::: "memory"); \
                   __builtin_amdgcn_s_barrier(); \
                   asm volatile("" ::: "memory"); } while (0)

// kernel 0: split W fp32 -> fp16 (h, l*2^11), packed per K=64 chunk
// (R17-R22-proven verbatim): chunk c (8192 halfs) = Wh[(kh*4+t4)*512 +
// m16*32 + slot*8] (4096) || Wl (4096), slot = (kb + (m16>>1)) & 3.
__global__ void split_w_kernel(const float* __restrict__ W,
                               _Float16* __restrict__ wsg) {
    int t = blockIdx.x * blockDim.x + threadIdx.x;   // 32c*2kh*4t4*16m*4kb = 16384
    if (t >= 16384) return;
    const int c   = t >> 9;
    const int kh  = (t >> 8) & 1;
    const int t4  = (t >> 6) & 3;
    const int m16 = (t >> 2) & 15;
    const int kb  = t & 3;
    const int slot = (kb + (m16 >> 1)) & 3;
    _Float16* dh = wsg + (size_t)c * 8192 + (kh * 4 + t4) * 512 + m16 * 32 + slot * 8;
    _Float16* dl = dh + 4096;
    const float* s = W + (size_t)(t4 * 16 + m16) * D_DIM + c * 64 + kh * 32 + kb * 8;
#pragma unroll
    for (int i = 0; i < 8; ++i) {
        float f = s[i];
        _Float16 h = (_Float16)f;
        dh[i] = h;
        dl[i] = (_Float16)((f - (float)h) * 2048.0f);
    }
}

// kernel 1: fused fp16x3 MFMA router — R20 numerics verbatim (proven absmax
// 4.9e-4). ONLY change: paired chunks, 1 barrier + 1 vmcnt per 2 chunks.
// Schedule: STAGE(c+2); VM(2); BAR; STAGE(c+3); COMPUTE(c); COMPUTE(c+1).
// NBUF=5 safety: S(c+2) overwrites chunk c-3's buf (readers at iter c-4,
// before BAR(c-2)); S(c+3) overwrites chunk c-2's buf (readers before
// BAR(c), which precedes the stage). Every thread: exactly 2 GLL per STAGE.
__launch_bounds__(1024)
__global__ void router_kernel(const float* __restrict__ x,
                              const _Float16* __restrict__ wsg,
                              const float* __restrict__ bias,
                              float* __restrict__ out_idx,
                              float* __restrict__ out_w)
{
    __shared__ __align__(16) float    xs[NBUF][4096];   // 80 KB x chunks [64r][64k] swz
    __shared__ __align__(16) _Float16 wh[NBUF][8192];   // 80 KB Wh||Wl chunks

    const int tid  = threadIdx.x;
    const int w    = tid >> 6;        // wave 0..15
    const int rh   = w >> 2;          // row quarter 0..3 (16 rows)
    const int kh   = (w >> 1) & 1;    // K half within chunk
    const int eh   = w & 1;           // expert half (tiles eh*2, eh*2+1)
    const int lane = tid & 63;
    const int m16  = lane & 15;
    const int kb   = lane >> 4;
    const int row0 = blockIdx.x * RPB;

    // x staging: thread stages granule gidx (16B) at LDS float pos gidx*4,
    // from the inverse-swizzled global position (slot = (quad + row) & 7)
    const int gidx = tid;                   // 0..1023
    const int gr = gidx >> 4;               // row 0..63
    const int gs = gidx & 15;
    const int gh = gs >> 3;                 // k-half of granule
    const int gq = ((gs & 7) - gr) & 7;     // global quad for this slot
    const float*    xsrc = x + (size_t)(row0 + gr) * D_DIM + gh * 32 + gq * 4;
    const _Float16* wsrc = wsg + (size_t)tid * 8;

#define STAGE(c, b) do { \
        GLL(xsrc + (size_t)(c) * 64, &xs[b][w * 256]); \
        GLL(wsrc + (size_t)(c) * 8192, &wh[b][w * 512]); \
    } while (0)

    f32x4 accHH[2], accHL[2], accLH[2];
#pragma unroll
    for (int q = 0; q < 2; ++q) {
        accHH[q] = (f32x4)0.0f; accHL[q] = (f32x4)0.0f; accLH[q] = (f32x4)0.0f;
    }

#define COMPUTE(b) do { \
        const int rr = rh * 16 + m16; \
        const int p0 = rr * 16 + kh * 8 + ((kb * 2 + rr) & 7); \
        const int p1 = rr * 16 + kh * 8 + ((kb * 2 + 1 + rr) & 7); \
        const float4 f0 = *(const float4*)&xs[b][p0 * 4]; \
        const float4 f1 = *(const float4*)&xs[b][p1 * 4]; \
        const float v[8] = {f0.x, f0.y, f0.z, f0.w, f1.x, f1.y, f1.z, f1.w}; \
        half8 xh, xl; \
        _Pragma("unroll") \
        for (int i = 0; i < 8; ++i) { \
            _Float16 h = (_Float16)v[i]; \
            xh[i] = h; \
            xl[i] = (_Float16)((v[i] - (float)h) * 2048.0f); \
        } \
        _Pragma("unroll") \
        for (int q = 0; q < 2; ++q) { \
            const int et = eh * 2 + q; \
            const int boff = (kh * 4 + et) * 512 + m16 * 32 + ((kb + (m16 >> 1)) & 3) * 8; \
            const half8 bh = *(const half8*)&wh[b][boff]; \
            const half8 bl = *(const half8*)&wh[b][4096 + boff]; \
            accHH[q] = __builtin_amdgcn_mfma_f32_16x16x32_f16(xh, bh, accHH[q], 0, 0, 0); \
            accHL[q] = __builtin_amdgcn_mfma_f32_16x16x32_f16(xh, bl, accHL[q], 0, 0, 0); \
            accLH[q] = __builtin_amdgcn_mfma_f32_16x16x32_f16(xl, bh, accLH[q], 0, 0, 0); \
        } \
    } while (0)

    // prologue: stage chunks 0,1
    STAGE(0, 0); STAGE(1, 1);

    for (int c = 0; c < NCH; c += 2) {
        if (c + 2 < NCH) { STAGE(c + 2, (c + 2) % NBUF); VM(2); }
        else             VM(0);
        BAR();           // chunks c, c+1 landed for all waves; overwritten
                         // buffers' readers all pre-date an earlier barrier
        if (c + 3 < NCH) STAGE(c + 3, (c + 3) % NBUF);  // issue under compute
        COMPUTE(c % NBUF);
        COMPUTE((c + 1) % NBUF);
    }
#undef STAGE
#undef COMPUTE
    BAR();               // K-loop LDS reads done before overlay writes

    // ---- epilogue: lg/bias overlay the xs buffers ----
    float* lgp = (float*)&xs[0][0];        // RPB*68 = 4352 floats
    float* bsp = lgp + RPB * 68;           // 64 floats

    if (tid < N_EXP) bsp[tid] = bias[tid];

    const float inv2048 = 1.0f / 2048.0f;
    // 2-phase kh reduction (D frag: row = rh*16 + kb*4 + r, col = (eh*2+q)*16+m16)
    if (kh == 0) {
#pragma unroll
        for (int q = 0; q < 2; ++q)
#pragma unroll
            for (int r = 0; r < 4; ++r)
                lgp[(rh * 16 + kb * 4 + r) * 68 + (eh * 2 + q) * 16 + m16] =
                    accHH[q][r] + (accHL[q][r] + accLH[q][r]) * inv2048;
    }
    __syncthreads();
    if (kh == 1) {
#pragma unroll
        for (int q = 0; q < 2; ++q)
#pragma unroll
            for (int r = 0; r < 4; ++r)
                lgp[(rh * 16 + kb * 4 + r) * 68 + (eh * 2 + q) * 16 + m16] +=
                    accHH[q][r] + (accHL[q][r] + accLH[q][r]) * inv2048;
    }
    __syncthreads();

    // sigmoid in place (64 rows x 64 experts; threads 0..511)
    if (tid < RPB * 8) {
        const int rg = tid >> 3, sl = tid & 7;
#pragma unroll
        for (int j = 0; j < 8; ++j) {
            const int idx = rg * 68 + sl * 8 + j;
            lgp[idx] = 1.0f / (1.0f + expf(-lgp[idx]));
        }
    }
    __syncthreads();

    // grouped top-k: R7-proven parallel selection (ties -> lower index)
    if (tid < RPB * 8) {
        const int rg = tid >> 3;
        const int sl = tid & 7;
        const int row = row0 + rg;

        float bsc[8];
        float gm = -INFINITY;
#pragma unroll
        for (int j = 0; j < 8; ++j) {
            bsc[j] = lgp[rg * 68 + sl * 8 + j] + bsp[sl * 8 + j];
            gm = fmaxf(gm, bsc[j]);
        }

        int grank = 0;
#pragma unroll
        for (int s = 1; s < 8; ++s) {
            float og = __shfl_xor(gm, s, 8);
            int   osl = sl ^ s;
            if (og > gm || (og == gm && osl < sl)) ++grank;
        }
        unsigned alive = (grank < TOPK_G) ? 0xFFu : 0u;

        float wsum = 0.f;
        float myw = 0.f;
        const int orow = row * TOPK;
        for (int k = 0; k < TOPK; ++k) {
            float bv = -INFINITY; int be = 9999;
#pragma unroll
            for (int j = 0; j < 8; ++j) {
                if (alive & (1u << j)) {
                    if (bsc[j] > bv) { bv = bsc[j]; be = sl * 8 + j; }
                }
            }
#pragma unroll
            for (int s = 1; s < 8; s <<= 1) {
                float ov = __shfl_xor(bv, s, 8);
                int   oe = __shfl_xor(be, s, 8);
                if (ov > bv || (ov == bv && oe < be)) { bv = ov; be = oe; }
            }
            const float wr = lgp[rg * 68 + be];
            wsum += wr;
            if ((be >> 3) == sl) alive &= ~(1u << (be & 7));
            if (sl == k) { out_idx[orow + k] = (float)be; myw = wr; }
        }
        const float inv = 1.0f / (wsum + 1e-20f);
        out_w[orow + sl] = myw * inv;
    }
}

extern "C" void kernel_launch(void* const* d_in, const int* in_sizes, int n_in,
                              void* d_out, int out_size, void* d_ws, size_t ws_size,
                              hipStream_t stream) {
    const float* x    = (const float*)d_in[0];
    const float* W    = (const float*)d_in[1];
    const float* bias = (const float*)d_in[2];
    float* out = (float*)d_out;
    _Float16* wsg = (_Float16*)d_ws;   // 512 KB fragment-packed W halves

    hipLaunchKernelGGL(split_w_kernel, dim3(16384 / 256), dim3(256),
                       0, stream, W, wsg);
    hipLaunchKernelGGL(router_kernel, dim3(S_TOT / RPB), dim3(1024),
                       0, stream, x, wsg, bias, out, out + S_TOT * TOPK);
}

// Round 25
// 38.862 us; speedup vs baseline: 1.0423x; 1.0423x over previous
//
#include <hip/hip_runtime.h>
#include <math.h>

#define N_EXP 64
#define TOPK 8
#define TOPK_G 4
#define D_DIM 2048
#define S_TOT 16384
#define RPB 64            // rows per block
#define NBUF 4            // LDS pipeline depth
#define NCH 32            // K chunks of 64

typedef _Float16 half8 __attribute__((ext_vector_type(8)));
typedef float f32x4 __attribute__((ext_vector_type(4)));

typedef __attribute__((address_space(1))) const unsigned int ga_u32;
typedef __attribute__((address_space(3))) unsigned int ls_u32;
#define GLL(src, dst) \
    __builtin_amdgcn_global_load_lds((ga_u32*)(src), (ls_u32*)(dst), 16, 0, 0)
#define VM(n) asm volatile("s_waitcnt vmcnt(" #n ")" ::: "memory")
#define BAR() do { asm volatile("" ::: "memory"); \
                   __builtin_amdgcn_s_barrier(); \
                   asm volatile("" ::: "memory"); } while (0)

// kernel 0: split W fp32 -> fp16 (h, l*2^11), packed per K=64 chunk
// (R17/R18/R19-proven verbatim): chunk c (8192 halfs) = Wh[(kh*4+t4)*512 +
// m16*32 + slot*8] (4096) || Wl (4096), slot = (kb + (m16>>1)) & 3.
__global__ void split_w_kernel(const float* __restrict__ W,
                               _Float16* __restrict__ wsg) {
    int t = blockIdx.x * blockDim.x + threadIdx.x;   // 32c*2kh*4t4*16m*4kb = 16384
    if (t >= 16384) return;
    const int c   = t >> 9;
    const int kh  = (t >> 8) & 1;
    const int t4  = (t >> 6) & 3;
    const int m16 = (t >> 2) & 15;
    const int kb  = t & 3;
    const int slot = (kb + (m16 >> 1)) & 3;
    _Float16* dh = wsg + (size_t)c * 8192 + (kh * 4 + t4) * 512 + m16 * 32 + slot * 8;
    _Float16* dl = dh + 4096;
    const float* s = W + (size_t)(t4 * 16 + m16) * D_DIM + c * 64 + kh * 32 + kb * 8;
#pragma unroll
    for (int i = 0; i < 8; ++i) {
        float f = s[i];
        _Float16 h = (_Float16)f;
        dh[i] = h;
        dl[i] = (_Float16)((f - (float)h) * 2048.0f);
    }
}

// kernel 1: fused fp16x3 MFMA router — R20 verbatim (session best: 38.8us,
// absmax 4.9e-4). Wave = (rh 0..3, kh 0..1, eh 0..1): 16 rows, 2 expert
// tiles, x split once per element. NBUF=4, lookahead 2, single barrier/chunk
// (trailing barrier provably redundant at this depth), VM(4).
// At the vmem-delivery roofline: 1 MB/CU (x 512K + W 512K, byte-optimal at
// R=E=64) at ~31 GB/s/CU ≈ measured fill-kernel delivery ceiling.
__launch_bounds__(1024)
__global__ void router_kernel(const float* __restrict__ x,
                              const _Float16* __restrict__ wsg,
                              const float* __restrict__ bias,
                              float* __restrict__ out_idx,
                              float* __restrict__ out_w)
{
    __shared__ __align__(16) float    xs[NBUF][4096];   // 64 KB x chunks [64r][64k] swz
    __shared__ __align__(16) _Float16 wh[NBUF][8192];   // 64 KB Wh||Wl chunks

    const int tid  = threadIdx.x;
    const int w    = tid >> 6;        // wave 0..15
    const int rh   = w >> 2;          // row quarter 0..3 (16 rows)
    const int kh   = (w >> 1) & 1;    // K half within chunk
    const int eh   = w & 1;           // expert half (tiles eh*2, eh*2+1)
    const int lane = tid & 63;
    const int m16  = lane & 15;
    const int kb   = lane >> 4;
    const int row0 = blockIdx.x * RPB;

    // x staging: thread stages granule gidx (16B) at LDS float pos gidx*4,
    // from the inverse-swizzled global position (slot = (quad + row) & 7)
    const int gidx = tid;                   // 0..1023
    const int gr = gidx >> 4;               // row 0..63
    const int gs = gidx & 15;
    const int gh = gs >> 3;                 // k-half of granule
    const int gq = ((gs & 7) - gr) & 7;     // global quad for this slot
    const float*    xsrc = x + (size_t)(row0 + gr) * D_DIM + gh * 32 + gq * 4;
    const _Float16* wsrc = wsg + (size_t)tid * 8;

#define STAGE(c, b) do { \
        GLL(xsrc + (size_t)(c) * 64, &xs[b][w * 256]); \
        GLL(wsrc + (size_t)(c) * 8192, &wh[b][w * 512]); \
    } while (0)

    f32x4 accHH[2], accHL[2], accLH[2];
#pragma unroll
    for (int q = 0; q < 2; ++q) {
        accHH[q] = (f32x4)0.0f; accHL[q] = (f32x4)0.0f; accLH[q] = (f32x4)0.0f;
    }

#define COMPUTE(b) do { \
        const int rr = rh * 16 + m16; \
        const int p0 = rr * 16 + kh * 8 + ((kb * 2 + rr) & 7); \
        const int p1 = rr * 16 + kh * 8 + ((kb * 2 + 1 + rr) & 7); \
        const float4 f0 = *(const float4*)&xs[b][p0 * 4]; \
        const float4 f1 = *(const float4*)&xs[b][p1 * 4]; \
        const float v[8] = {f0.x, f0.y, f0.z, f0.w, f1.x, f1.y, f1.z, f1.w}; \
        half8 xh, xl; \
        _Pragma("unroll") \
        for (int i = 0; i < 8; ++i) { \
            _Float16 h = (_Float16)v[i]; \
            xh[i] = h; \
            xl[i] = (_Float16)((v[i] - (float)h) * 2048.0f); \
        } \
        _Pragma("unroll") \
        for (int q = 0; q < 2; ++q) { \
            const int et = eh * 2 + q; \
            const int boff = (kh * 4 + et) * 512 + m16 * 32 + ((kb + (m16 >> 1)) & 3) * 8; \
            const half8 bh = *(const half8*)&wh[b][boff]; \
            const half8 bl = *(const half8*)&wh[b][4096 + boff]; \
            accHH[q] = __builtin_amdgcn_mfma_f32_16x16x32_f16(xh, bh, accHH[q], 0, 0, 0); \
            accHL[q] = __builtin_amdgcn_mfma_f32_16x16x32_f16(xh, bl, accHL[q], 0, 0, 0); \
            accLH[q] = __builtin_amdgcn_mfma_f32_16x16x32_f16(xl, bh, accLH[q], 0, 0, 0); \
        } \
    } while (0)

    // prologue: stage chunks 0,1
    STAGE(0, 0); STAGE(1, 1);

    for (int c = 0; c < NCH; ++c) {
        if (c + 2 < NCH)        { STAGE(c + 2, (c + 2) & 3); VM(4); }
        else if (c == NCH - 2)  VM(2);
        else                    VM(0);
        BAR();               // all waves' chunk-c DMA landed; buffer (c-2)%4
                             // safely re-staged (readers pre-date BAR(c-1))
        COMPUTE(c & 3);
    }
#undef STAGE
#undef COMPUTE
    BAR();                   // K-loop LDS reads done before overlay writes

    // ---- epilogue: lg/bias overlay the xs buffers ----
    float* lgp = (float*)&xs[0][0];        // RPB*68 = 4352 floats
    float* bsp = lgp + RPB * 68;           // 64 floats

    if (tid < N_EXP) bsp[tid] = bias[tid];

    const float inv2048 = 1.0f / 2048.0f;
    // 2-phase kh reduction (D frag: row = rh*16 + kb*4 + r, col = (eh*2+q)*16+m16)
    if (kh == 0) {
#pragma unroll
        for (int q = 0; q < 2; ++q)
#pragma unroll
            for (int r = 0; r < 4; ++r)
                lgp[(rh * 16 + kb * 4 + r) * 68 + (eh * 2 + q) * 16 + m16] =
                    accHH[q][r] + (accHL[q][r] + accLH[q][r]) * inv2048;
    }
    __syncthreads();
    if (kh == 1) {
#pragma unroll
        for (int q = 0; q < 2; ++q)
#pragma unroll
            for (int r = 0; r < 4; ++r)
                lgp[(rh * 16 + kb * 4 + r) * 68 + (eh * 2 + q) * 16 + m16] +=
                    accHH[q][r] + (accHL[q][r] + accLH[q][r]) * inv2048;
    }
    __syncthreads();

    // sigmoid in place (64 rows x 64 experts; threads 0..511)
    if (tid < RPB * 8) {
        const int rg = tid >> 3, sl = tid & 7;
#pragma unroll
        for (int j = 0; j < 8; ++j) {
            const int idx = rg * 68 + sl * 8 + j;
            lgp[idx] = 1.0f / (1.0f + expf(-lgp[idx]));
        }
    }
    __syncthreads();

    // grouped top-k: R7-proven parallel selection (ties -> lower index)
    if (tid < RPB * 8) {
        const int rg = tid >> 3;
        const int sl = tid & 7;
        const int row = row0 + rg;

        float bsc[8];
        float gm = -INFINITY;
#pragma unroll
        for (int j = 0; j < 8; ++j) {
            bsc[j] = lgp[rg * 68 + sl * 8 + j] + bsp[sl * 8 + j];
            gm = fmaxf(gm, bsc[j]);
        }

        int grank = 0;
#pragma unroll
        for (int s = 1; s < 8; ++s) {
            float og = __shfl_xor(gm, s, 8);
            int   osl = sl ^ s;
            if (og > gm || (og == gm && osl < sl)) ++grank;
        }
        unsigned alive = (grank < TOPK_G) ? 0xFFu : 0u;

        float wsum = 0.f;
        float myw = 0.f;
        const int orow = row * TOPK;
        for (int k = 0; k < TOPK; ++k) {
            float bv = -INFINITY; int be = 9999;
#pragma unroll
            for (int j = 0; j < 8; ++j) {
                if (alive & (1u << j)) {
                    if (bsc[j] > bv) { bv = bsc[j]; be = sl * 8 + j; }
                }
            }
#pragma unroll
            for (int s = 1; s < 8; s <<= 1) {
                float ov = __shfl_xor(bv, s, 8);
                int   oe = __shfl_xor(be, s, 8);
                if (ov > bv || (ov == bv && oe < be)) { bv = ov; be = oe; }
            }
            const float wr = lgp[rg * 68 + be];
            wsum += wr;
            if ((be >> 3) == sl) alive &= ~(1u << (be & 7));
            if (sl == k) { out_idx[orow + k] = (float)be; myw = wr; }
        }
        const float inv = 1.0f / (wsum + 1e-20f);
        out_w[orow + sl] = myw * inv;
    }
}

extern "C" void kernel_launch(void* const* d_in, const int* in_sizes, int n_in,
                              void* d_out, int out_size, void* d_ws, size_t ws_size,
                              hipStream_t stream) {
    const float* x    = (const float*)d_in[0];
    const float* W    = (const float*)d_in[1];
    const float* bias = (const float*)d_in[2];
    float* out = (float*)d_out;
    _Float16* wsg = (_Float16*)d_ws;   // 512 KB fragment-packed W halves

    hipLaunchKernelGGL(split_w_kernel, dim3(16384 / 256), dim3(256),
                       0, stream, W, wsg);
    hipLaunchKernelGGL(router_kernel, dim3(S_TOT / RPB), dim3(1024),
                       0, stream, x, wsg, bias, out, out + S_TOT * TOPK);
}